// Round 1
// baseline (69.130 us; speedup 1.0000x reference)
//
#include <hip/hip_runtime.h>

#define POOL 7
#define SAMP 2
#define DIMS 5
#define SCALE 0.0625f

// x: [B, C=245, H, W] f32; boxes: [B, N, 4] f32; out: [B*N, 5, 7, 7] f32.
// One thread per output element. Output flat index == (r*245 + c) where the
// input channel c = d*49 + ph*7 + pw equals the output channel layout, so no
// index remap is needed.
__global__ __launch_bounds__(256) void psroi_kernel(
    const float* __restrict__ x, const float* __restrict__ boxes,
    float* __restrict__ out, int total, int C, int H, int W, int N)
{
    int idx = blockIdx.x * blockDim.x + threadIdx.x;
    if (idx >= total) return;

    int r = idx / C;
    int c = idx - r * C;           // c = d*49 + ph*7 + pw
    int ph = (c / POOL) % POOL;
    int pw = c % POOL;
    int b = r / N;

    const float* bx = boxes + (size_t)r * 4;
    float sw = bx[0] * SCALE - 0.5f;
    float sh = bx[1] * SCALE - 0.5f;
    float ew = bx[2] * SCALE - 0.5f;
    float eh = bx[3] * SCALE - 0.5f;
    float bin_h = (eh - sh) / (float)POOL;
    float bin_w = (ew - sw) / (float)POOL;

    const float* xp = x + ((size_t)b * C + c) * (size_t)(H * W);

    float fy0 = sh + (float)ph * bin_h;   // bin start (y)
    float fx0 = sw + (float)pw * bin_w;   // bin start (x)

    float sum = 0.f;
    #pragma unroll
    for (int iy = 0; iy < SAMP; ++iy) {
        float y = fy0 + ((float)iy + 0.5f) * bin_h / (float)SAMP;
        bool vy = (y >= -1.0f) && (y <= (float)H);
        float yc = fminf(fmaxf(y, 0.0f), (float)(H - 1));
        int   yl = (int)floorf(yc);
        float ly = yc - (float)yl;
        float hy = 1.0f - ly;
        int   yh = min(yl + 1, H - 1);
        const float* row_l = xp + (size_t)yl * W;
        const float* row_h = xp + (size_t)yh * W;
        #pragma unroll
        for (int ix = 0; ix < SAMP; ++ix) {
            float xf = fx0 + ((float)ix + 0.5f) * bin_w / (float)SAMP;
            bool vx = (xf >= -1.0f) && (xf <= (float)W);
            float xc = fminf(fmaxf(xf, 0.0f), (float)(W - 1));
            int   xl = (int)floorf(xc);
            float lx = xc - (float)xl;
            float hx = 1.0f - lx;
            int   xh = min(xl + 1, W - 1);

            float v11 = row_l[xl];
            float v12 = row_l[xh];
            float v21 = row_h[xl];
            float v22 = row_h[xh];

            float val = hy * hx * v11 + hy * lx * v12
                      + ly * hx * v21 + ly * lx * v22;
            if (vy && vx) sum += val;
        }
    }
    out[idx] = sum * 0.25f;
}

extern "C" void kernel_launch(void* const* d_in, const int* in_sizes, int n_in,
                              void* d_out, int out_size, void* d_ws, size_t ws_size,
                              hipStream_t stream) {
    const float* x     = (const float*)d_in[0];
    const float* boxes = (const float*)d_in[1];
    float* out = (float*)d_out;

    const int B = 8, C = 245, H = 100, W = 100, N = 512;
    int total = B * N * C;   // 1,003,520 == out_size
    (void)B; (void)in_sizes; (void)n_in; (void)out_size; (void)d_ws; (void)ws_size;

    dim3 block(256);
    dim3 grid((total + 255) / 256);
    hipLaunchKernelGGL(psroi_kernel, grid, block, 0, stream,
                       x, boxes, out, total, C, H, W, N);
}

// Round 2
// 39.025 us; speedup vs baseline: 1.7714x; 1.7714x over previous
//
#include <hip/hip_runtime.h>

#define POOL 7
#define SAMP 2
#define DIMS 5
#define SCALE 0.0625f
#define NXCD 8

// x: [B, C=245, H, W] f32; boxes: [B, N, 4] f32; out: [B*N, 5, 7, 7] f32.
//
// Mapping (round 2): one block = one (b,c) plane x 256 rois, so the block's
// read footprint is a single 40KB channel plane (L1/L2 resident) and the
// cross-roi overlap of bin (ph,pw) regions within that plane is captured.
// XCD-affinity swizzle: plane % 8 == blockIdx % 8 (bid%8 -> XCD heuristic),
// and the two half-roi blocks of a plane are 8 apart in dispatch order
// (near-simultaneous on the same XCD).
__global__ __launch_bounds__(256) void psroi_kernel(
    const float* __restrict__ x, const float* __restrict__ boxes,
    float* __restrict__ out, int C, int H, int W, int N)
{
    int bid = blockIdx.x;
    int xcd = bid & 7;          // target XCD
    int j   = bid >> 3;         // sequence within XCD
    int k   = j >> 1;           // plane sequence on this XCD [0,245)
    int h   = j & 1;            // roi half (0: rois 0..255, 1: 256..511)
    int p   = k * NXCD + xcd;   // plane id in [0, 1960)
    int b   = p / 245;          // batch
    int c   = p - b * 245;      // channel = d*49 + ph*7 + pw
    int ph  = (c / POOL) % POOL;
    int pw  = c % POOL;

    int n = h * 256 + threadIdx.x;   // roi within batch [0,512)
    int r = b * N + n;               // global roi id

    const float* bx = boxes + (size_t)r * 4;
    float sw = bx[0] * SCALE - 0.5f;
    float sh = bx[1] * SCALE - 0.5f;
    float ew = bx[2] * SCALE - 0.5f;
    float eh = bx[3] * SCALE - 0.5f;
    float bin_h = (eh - sh) / (float)POOL;
    float bin_w = (ew - sw) / (float)POOL;

    const float* xp = x + ((size_t)b * 245 + c) * (size_t)(H * W);

    float fy0 = sh + (float)ph * bin_h;   // bin start (y)
    float fx0 = sw + (float)pw * bin_w;   // bin start (x)

    float sum = 0.f;
    #pragma unroll
    for (int iy = 0; iy < SAMP; ++iy) {
        float y = fy0 + ((float)iy + 0.5f) * bin_h / (float)SAMP;
        bool vy = (y >= -1.0f) && (y <= (float)H);
        float yc = fminf(fmaxf(y, 0.0f), (float)(H - 1));
        int   yl = (int)floorf(yc);
        float ly = yc - (float)yl;
        float hy = 1.0f - ly;
        int   yh = min(yl + 1, H - 1);
        const float* row_l = xp + (size_t)yl * W;
        const float* row_h = xp + (size_t)yh * W;
        #pragma unroll
        for (int ix = 0; ix < SAMP; ++ix) {
            float xf = fx0 + ((float)ix + 0.5f) * bin_w / (float)SAMP;
            bool vx = (xf >= -1.0f) && (xf <= (float)W);
            float xc = fminf(fmaxf(xf, 0.0f), (float)(W - 1));
            int   xl = (int)floorf(xc);
            float lx = xc - (float)xl;
            float hx = 1.0f - lx;
            int   xh = min(xl + 1, W - 1);

            float v11 = row_l[xl];
            float v12 = row_l[xh];
            float v21 = row_h[xl];
            float v22 = row_h[xh];

            float val = hy * hx * v11 + hy * lx * v12
                      + ly * hx * v21 + ly * lx * v22;
            if (vy && vx) sum += val;
        }
    }
    out[(size_t)r * 245 + c] = sum * 0.25f;
}

extern "C" void kernel_launch(void* const* d_in, const int* in_sizes, int n_in,
                              void* d_out, int out_size, void* d_ws, size_t ws_size,
                              hipStream_t stream) {
    const float* x     = (const float*)d_in[0];
    const float* boxes = (const float*)d_in[1];
    float* out = (float*)d_out;

    const int C = 245, H = 100, W = 100, N = 512;
    // 1960 planes x 2 half-roi blocks = 3920 blocks of 256 threads
    int nblocks = 8 * 245 * 2 / 1;  // = 3920
    (void)in_sizes; (void)n_in; (void)out_size; (void)d_ws; (void)ws_size;

    dim3 block(256);
    dim3 grid(nblocks);
    hipLaunchKernelGGL(psroi_kernel, grid, block, 0, stream,
                       x, boxes, out, C, H, W, N);
}

// Round 3
// 26.123 us; speedup vs baseline: 2.6463x; 1.4939x over previous
//
#include <hip/hip_runtime.h>

#define POOL 7
#define SCALE 0.0625f
#define HW 10000   // 100*100 plane elements

// x: [B=8, C=245, H=100, W=100] f32; boxes: [B, N=512, 4] f32;
// out: [B*N, 5, 7, 7] f32 (channel c = d*49+ph*7+pw matches output layout).
//
// Round 3 mapping: one block = one (b,c) plane, 512 threads = 512 rois.
// The 40KB plane is staged into LDS with coalesced float4 loads; all 16
// bilinear taps per thread become ds_read_b32 (no TA line-serialization on
// divergent addresses). 40KB LDS/block -> 4 blocks/CU x 8 waves = 32 waves/CU.
__global__ __launch_bounds__(512) void psroi_kernel(
    const float* __restrict__ x, const float* __restrict__ boxes,
    float* __restrict__ out, int H, int W)
{
    __shared__ float plane[HW];

    int p = blockIdx.x;          // plane id in [0, 1960)
    int b = p / 245;             // batch
    int c = p - b * 245;         // channel = d*49 + ph*7 + pw
    int ph = (c / POOL) % POOL;
    int pw = c % POOL;

    // ---- stage plane into LDS: 2500 float4, fully coalesced ----
    const float4* __restrict__ src4 = (const float4*)(x + (size_t)p * HW);
    float4* dst4 = (float4*)plane;
    #pragma unroll
    for (int i = 0; i < 5; ++i) {
        int j = threadIdx.x + i * 512;
        if (j < HW / 4) dst4[j] = src4[j];
    }
    __syncthreads();

    // ---- one thread per roi ----
    int n = threadIdx.x;              // roi within batch [0,512)
    int r = b * 512 + n;              // global roi id

    float4 bx = *(const float4*)(boxes + (size_t)r * 4);
    float sw = bx.x * SCALE - 0.5f;
    float sh = bx.y * SCALE - 0.5f;
    float ew = bx.z * SCALE - 0.5f;
    float eh = bx.w * SCALE - 0.5f;
    float bin_h = (eh - sh) / (float)POOL;
    float bin_w = (ew - sw) / (float)POOL;

    float fy0 = sh + (float)ph * bin_h;   // bin start (y)
    float fx0 = sw + (float)pw * bin_w;   // bin start (x)

    float sum = 0.f;
    #pragma unroll
    for (int iy = 0; iy < 2; ++iy) {
        float y = fy0 + ((float)iy + 0.5f) * bin_h * 0.5f;
        bool vy = (y >= -1.0f) && (y <= (float)H);
        float yc = fminf(fmaxf(y, 0.0f), (float)(H - 1));
        int   yl = (int)floorf(yc);
        float ly = yc - (float)yl;
        float hy = 1.0f - ly;
        int   yh = min(yl + 1, H - 1);
        int rl = yl * W;
        int rh = yh * W;
        #pragma unroll
        for (int ix = 0; ix < 2; ++ix) {
            float xf = fx0 + ((float)ix + 0.5f) * bin_w * 0.5f;
            bool vx = (xf >= -1.0f) && (xf <= (float)W);
            float xc = fminf(fmaxf(xf, 0.0f), (float)(W - 1));
            int   xl = (int)floorf(xc);
            float lx = xc - (float)xl;
            float hx = 1.0f - lx;
            int   xh = min(xl + 1, W - 1);

            float v11 = plane[rl + xl];
            float v12 = plane[rl + xh];
            float v21 = plane[rh + xl];
            float v22 = plane[rh + xh];

            float val = hy * hx * v11 + hy * lx * v12
                      + ly * hx * v21 + ly * lx * v22;
            if (vy && vx) sum += val;
        }
    }
    out[(size_t)r * 245 + c] = sum * 0.25f;
}

extern "C" void kernel_launch(void* const* d_in, const int* in_sizes, int n_in,
                              void* d_out, int out_size, void* d_ws, size_t ws_size,
                              hipStream_t stream) {
    const float* x     = (const float*)d_in[0];
    const float* boxes = (const float*)d_in[1];
    float* out = (float*)d_out;

    const int H = 100, W = 100;
    (void)in_sizes; (void)n_in; (void)out_size; (void)d_ws; (void)ws_size;

    dim3 block(512);
    dim3 grid(8 * 245);   // one block per (b,c) plane = 1960
    hipLaunchKernelGGL(psroi_kernel, grid, block, 0, stream,
                       x, boxes, out, H, W);
}

// Round 4
// 23.908 us; speedup vs baseline: 2.8915x; 1.0927x over previous
//
#include <hip/hip_runtime.h>

#define POOL 7
#define SCALE 0.0625f
#define HW 10000      // 100*100 plane elements
#define NROI 512
#define NCH 245

// Kernel 1: one block = one (b,c) plane, 512 threads = 512 rois.
// Plane staged to LDS (coalesced float4); bilinear taps are paired
// ds_read2_b32 (always read (xl, xl+1): when xl==W-1 the x-high weight lx is
// exactly 0, so the extra element contributes nothing; LDS padded+zeroed so
// the very last pair never reads garbage).
// Output written COALESCED to ws[plane][roi]; kernel 2 transposes to
// out[roi][channel].
__global__ __launch_bounds__(512) void psroi_kernel(
    const float* __restrict__ x, const float* __restrict__ boxes,
    float* __restrict__ ws, int H, int W)
{
    __shared__ float plane[HW + 4];

    int p = blockIdx.x;          // plane id in [0, 1960)
    int b = p / NCH;             // batch
    int c = p - b * NCH;         // channel = d*49 + ph*7 + pw
    int ph = (c / POOL) % POOL;
    int pw = c % POOL;

    // ---- stage plane into LDS: 2500 float4, fully coalesced ----
    const float4* __restrict__ src4 = (const float4*)(x + (size_t)p * HW);
    float4* dst4 = (float4*)plane;
    #pragma unroll
    for (int i = 0; i < 5; ++i) {
        int j = threadIdx.x + i * 512;
        if (j < HW / 4) dst4[j] = src4[j];
    }
    if (threadIdx.x == 0) {
        plane[HW] = 0.f; plane[HW + 1] = 0.f;
        plane[HW + 2] = 0.f; plane[HW + 3] = 0.f;
    }
    __syncthreads();

    // ---- one thread per roi ----
    int n = threadIdx.x;              // roi within batch [0,512)
    int r = b * NROI + n;             // global roi id

    float4 bx = *(const float4*)(boxes + (size_t)r * 4);
    float sw = bx.x * SCALE - 0.5f;
    float sh = bx.y * SCALE - 0.5f;
    float ew = bx.z * SCALE - 0.5f;
    float eh = bx.w * SCALE - 0.5f;
    float bin_h = (eh - sh) / (float)POOL;
    float bin_w = (ew - sw) / (float)POOL;

    float fy0 = sh + (float)ph * bin_h;   // bin start (y)
    float fx0 = sw + (float)pw * bin_w;   // bin start (x)

    float sum = 0.f;
    #pragma unroll
    for (int iy = 0; iy < 2; ++iy) {
        float y = fy0 + ((float)iy + 0.5f) * bin_h * 0.5f;
        bool vy = (y >= -1.0f) && (y <= (float)H);
        float yc = fminf(fmaxf(y, 0.0f), (float)(H - 1));
        int   yl = (int)floorf(yc);
        float ly = yc - (float)yl;
        float hy = 1.0f - ly;
        int   yh = min(yl + 1, H - 1);
        int rl = yl * W;
        int rh = yh * W;
        #pragma unroll
        for (int ix = 0; ix < 2; ++ix) {
            float xf = fx0 + ((float)ix + 0.5f) * bin_w * 0.5f;
            bool vx = (xf >= -1.0f) && (xf <= (float)W);
            float xc = fminf(fmaxf(xf, 0.0f), (float)(W - 1));
            int   xl = (int)floorf(xc);
            float lx = xc - (float)xl;    // == 0 exactly when xl == W-1
            float hx = 1.0f - lx;

            int a0 = rl + xl;
            int a1 = rh + xl;
            float v11 = plane[a0];
            float v12 = plane[a0 + 1];    // weight lx == 0 if out of row
            float v21 = plane[a1];
            float v22 = plane[a1 + 1];

            float val = hy * hx * v11 + hy * lx * v12
                      + ly * hx * v21 + ly * lx * v22;
            if (vy && vx) sum += val;
        }
    }
    ws[(size_t)p * NROI + n] = sum * 0.25f;   // coalesced
}

// Kernel 2: per-batch transpose ws[b][c][n] -> out[b][n][c].
#define TILE 32
__global__ __launch_bounds__(256) void transpose_kernel(
    const float* __restrict__ ws, float* __restrict__ out)
{
    __shared__ float tile[TILE][TILE + 1];
    int b  = blockIdx.z;
    int c0 = blockIdx.y * TILE;       // channel tile base (0..244)
    int n0 = blockIdx.x * TILE;       // roi tile base (0..511)
    const float* in = ws + (size_t)b * NCH * NROI;
    float* ob = out + (size_t)b * NROI * NCH;
    int tx = threadIdx.x;             // 0..31
    int ty = threadIdx.y;             // 0..7

    #pragma unroll
    for (int k = 0; k < 4; ++k) {
        int cc = c0 + ty + k * 8;
        if (cc < NCH) tile[ty + k * 8][tx] = in[(size_t)cc * NROI + n0 + tx];
    }
    __syncthreads();
    #pragma unroll
    for (int k = 0; k < 4; ++k) {
        int nn = n0 + ty + k * 8;
        int cc = c0 + tx;
        if (cc < NCH) ob[(size_t)nn * NCH + cc] = tile[tx][ty + k * 8];
    }
}

extern "C" void kernel_launch(void* const* d_in, const int* in_sizes, int n_in,
                              void* d_out, int out_size, void* d_ws, size_t ws_size,
                              hipStream_t stream) {
    const float* x     = (const float*)d_in[0];
    const float* boxes = (const float*)d_in[1];
    float* out = (float*)d_out;
    float* ws  = (float*)d_ws;       // 1960*512 f32 = 4 MB

    const int H = 100, W = 100;
    (void)in_sizes; (void)n_in; (void)out_size; (void)ws_size;

    hipLaunchKernelGGL(psroi_kernel, dim3(8 * NCH), dim3(512), 0, stream,
                       x, boxes, ws, H, W);
    hipLaunchKernelGGL(transpose_kernel, dim3(NROI / TILE, (NCH + TILE - 1) / TILE, 8),
                       dim3(TILE, 8), 0, stream, ws, out);
}

// Round 5
// 22.503 us; speedup vs baseline: 3.0720x; 1.0625x over previous
//
#include <hip/hip_runtime.h>

#define POOL 7
#define SCALE 0.0625f
#define HW 10000      // 100*100 plane elements
#define NROI 512
#define NCH 245

typedef const __attribute__((address_space(1))) void* gas_ptr;
typedef __attribute__((address_space(3))) void* las_ptr;

// Kernel 1: one block = one (b,c) plane, 512 threads = 512 rois.
// Plane staged to LDS via global_load_lds (direct HBM->LDS DMA, width=16,
// linear dest = wave-uniform base + lane*16 -- matches our linear layout).
// Bilinear taps are paired ds_read2_b32 (always read (xl, xl+1): when
// xl==W-1 the x-high weight lx is exactly 0; LDS pad zeroed).
// Output written COALESCED to ws[plane][roi]; kernel 2 transposes.
__global__ __launch_bounds__(512) void psroi_kernel(
    const float* __restrict__ x, const float* __restrict__ boxes,
    float* __restrict__ ws, int H, int W)
{
    __shared__ float plane[HW + 4];

    int p = blockIdx.x;          // plane id in [0, 1960)
    int b = p / NCH;             // batch
    int c = p - b * NCH;         // channel = d*49 + ph*7 + pw
    int ph = (c / POOL) % POOL;
    int pw = c % POOL;

    // ---- stage plane into LDS: 2500 x 16B via global_load_lds ----
    const float4* __restrict__ src4 = (const float4*)(x + (size_t)p * HW);
    int lane = threadIdx.x & 63;
    int wave = threadIdx.x >> 6;
    #pragma unroll
    for (int i = 0; i < 5; ++i) {
        int chunk_base = i * 512 + wave * 64;   // float4 units, wave-uniform
        int chunk = chunk_base + lane;
        if (chunk < HW / 4) {
            __builtin_amdgcn_global_load_lds(
                (gas_ptr)(src4 + chunk),
                (las_ptr)((char*)plane + (size_t)chunk_base * 16),
                16, 0, 0);
        }
    }
    if (threadIdx.x < 4) plane[HW + threadIdx.x] = 0.f;
    __syncthreads();   // drains vmcnt before any LDS read

    // ---- one thread per roi ----
    int n = threadIdx.x;              // roi within batch [0,512)
    int r = b * NROI + n;             // global roi id

    float4 bx = *(const float4*)(boxes + (size_t)r * 4);
    float sw = bx.x * SCALE - 0.5f;
    float sh = bx.y * SCALE - 0.5f;
    float ew = bx.z * SCALE - 0.5f;
    float eh = bx.w * SCALE - 0.5f;
    float bin_h = (eh - sh) / (float)POOL;
    float bin_w = (ew - sw) / (float)POOL;

    float fy0 = sh + (float)ph * bin_h;   // bin start (y)
    float fx0 = sw + (float)pw * bin_w;   // bin start (x)

    float sum = 0.f;
    #pragma unroll
    for (int iy = 0; iy < 2; ++iy) {
        float y = fy0 + ((float)iy + 0.5f) * bin_h * 0.5f;
        bool vy = (y >= -1.0f) && (y <= (float)H);
        float yc = fminf(fmaxf(y, 0.0f), (float)(H - 1));
        int   yl = (int)floorf(yc);
        float ly = yc - (float)yl;
        float hy = 1.0f - ly;
        int   yh = min(yl + 1, H - 1);
        int rl = yl * W;
        int rh = yh * W;
        #pragma unroll
        for (int ix = 0; ix < 2; ++ix) {
            float xf = fx0 + ((float)ix + 0.5f) * bin_w * 0.5f;
            bool vx = (xf >= -1.0f) && (xf <= (float)W);
            float xc = fminf(fmaxf(xf, 0.0f), (float)(W - 1));
            int   xl = (int)floorf(xc);
            float lx = xc - (float)xl;    // == 0 exactly when xl == W-1
            float hx = 1.0f - lx;

            int a0 = rl + xl;
            int a1 = rh + xl;
            float v11 = plane[a0];
            float v12 = plane[a0 + 1];    // weight lx == 0 if out of row
            float v21 = plane[a1];
            float v22 = plane[a1 + 1];

            float val = hy * hx * v11 + hy * lx * v12
                      + ly * hx * v21 + ly * lx * v22;
            if (vy && vx) sum += val;
        }
    }
    ws[(size_t)p * NROI + n] = sum * 0.25f;   // coalesced
}

// Kernel 2: per-batch transpose ws[b][c][n] -> out[b][n][c].
#define TILE 32
__global__ __launch_bounds__(256) void transpose_kernel(
    const float* __restrict__ ws, float* __restrict__ out)
{
    __shared__ float tile[TILE][TILE + 1];
    int b  = blockIdx.z;
    int c0 = blockIdx.y * TILE;       // channel tile base (0..244)
    int n0 = blockIdx.x * TILE;       // roi tile base (0..511)
    const float* in = ws + (size_t)b * NCH * NROI;
    float* ob = out + (size_t)b * NROI * NCH;
    int tx = threadIdx.x;             // 0..31
    int ty = threadIdx.y;             // 0..7

    #pragma unroll
    for (int k = 0; k < 4; ++k) {
        int cc = c0 + ty + k * 8;
        if (cc < NCH) tile[ty + k * 8][tx] = in[(size_t)cc * NROI + n0 + tx];
    }
    __syncthreads();
    #pragma unroll
    for (int k = 0; k < 4; ++k) {
        int nn = n0 + ty + k * 8;
        int cc = c0 + tx;
        if (cc < NCH) ob[(size_t)nn * NCH + cc] = tile[tx][ty + k * 8];
    }
}

extern "C" void kernel_launch(void* const* d_in, const int* in_sizes, int n_in,
                              void* d_out, int out_size, void* d_ws, size_t ws_size,
                              hipStream_t stream) {
    const float* x     = (const float*)d_in[0];
    const float* boxes = (const float*)d_in[1];
    float* out = (float*)d_out;
    float* ws  = (float*)d_ws;       // 1960*512 f32 = 4 MB

    const int H = 100, W = 100;
    (void)in_sizes; (void)n_in; (void)out_size; (void)ws_size;

    hipLaunchKernelGGL(psroi_kernel, dim3(8 * NCH), dim3(512), 0, stream,
                       x, boxes, ws, H, W);
    hipLaunchKernelGGL(transpose_kernel, dim3(NROI / TILE, (NCH + TILE - 1) / TILE, 8),
                       dim3(TILE, 8), 0, stream, ws, out);
}

// Round 6
// 22.072 us; speedup vs baseline: 3.1320x; 1.0195x over previous
//
#include <hip/hip_runtime.h>

#define POOL 7
#define SCALE 0.0625f
#define HW 10000      // 100*100 plane elements
#define NROI 512
#define NCH 245

typedef const __attribute__((address_space(1))) void* gas_ptr;
typedef __attribute__((address_space(3))) void* las_ptr;

// Kernel 1: one block = one (b,c) plane, 512 threads = 512 rois.
// Order: boxes load issued FIRST, then 5 stage DMAs (global_load_lds w=16).
// In-order vmcnt retirement means the geometry VALU (which only needs boxes)
// runs at vmcnt(5) -- i.e. under the plane DMA latency. After the barrier the
// per-thread work is only 8 paired LDS reads + bilinear FMAs.
// Validity is folded into the weights (hy*=vy etc.), x-high tap uses the
// (xl, xl+1) pair trick (lx==0 exactly when xl==W-1; LDS pad zeroed).
__global__ __launch_bounds__(512) void psroi_kernel(
    const float* __restrict__ x, const float* __restrict__ boxes,
    float* __restrict__ ws, int H, int W)
{
    __shared__ float plane[HW + 4];

    int p = blockIdx.x;          // plane id in [0, 1960)
    int b = p / NCH;             // batch
    int c = p - b * NCH;         // channel = d*49 + ph*7 + pw
    int ph = (c / POOL) % POOL;
    int pw = c % POOL;

    int n = threadIdx.x;              // roi within batch [0,512)
    int r = b * NROI + n;             // global roi id

    // ---- issue boxes load FIRST (completes at vmcnt(5), before stage DMAs)
    float4 bx = *(const float4*)(boxes + (size_t)r * 4);

    // ---- stage plane into LDS: 2500 x 16B via global_load_lds ----
    const float4* __restrict__ src4 = (const float4*)(x + (size_t)p * HW);
    int lane = threadIdx.x & 63;
    int wave = threadIdx.x >> 6;
    #pragma unroll
    for (int i = 0; i < 5; ++i) {
        int chunk_base = i * 512 + wave * 64;   // float4 units, wave-uniform
        int chunk = chunk_base + lane;
        if (chunk < HW / 4) {
            __builtin_amdgcn_global_load_lds(
                (gas_ptr)(src4 + chunk),
                (las_ptr)((char*)plane + (size_t)chunk_base * 16),
                16, 0, 0);
        }
    }
    if (threadIdx.x < 4) plane[HW + threadIdx.x] = 0.f;

    // ---- per-roi geometry: runs under the stage DMA (needs only boxes) ----
    float sw = bx.x * SCALE - 0.5f;
    float sh = bx.y * SCALE - 0.5f;
    float ew = bx.z * SCALE - 0.5f;
    float eh = bx.w * SCALE - 0.5f;
    float bin_h = (eh - sh) / (float)POOL;
    float bin_w = (ew - sw) / (float)POOL;
    float fy0 = sh + (float)ph * bin_h;
    float fx0 = sw + (float)pw * bin_w;

    int   rowa[2];    // row base for y-low; y-high = rowa+rstep
    int   rstep[2];
    float wyh[2], wyl[2];
    #pragma unroll
    for (int iy = 0; iy < 2; ++iy) {
        float y  = fy0 + ((float)iy + 0.5f) * bin_h * 0.5f;
        float vy = (y >= -1.0f && y <= (float)H) ? 1.0f : 0.0f;
        float yc = fminf(fmaxf(y, 0.0f), (float)(H - 1));
        int   yl = (int)floorf(yc);
        float ly = yc - (float)yl;
        wyl[iy] = ly * vy;
        wyh[iy] = (1.0f - ly) * vy;
        rowa[iy]  = yl * W;
        rstep[iy] = (yl < H - 1) ? W : 0;
    }
    int   colx[2];
    float wxh[2], wxl[2];
    #pragma unroll
    for (int ix = 0; ix < 2; ++ix) {
        float xf = fx0 + ((float)ix + 0.5f) * bin_w * 0.5f;
        float vx = (xf >= -1.0f && xf <= (float)W) ? 1.0f : 0.0f;
        float xc = fminf(fmaxf(xf, 0.0f), (float)(W - 1));
        int   xl = (int)floorf(xc);
        float lx = xc - (float)xl;      // == 0 exactly when xl == W-1
        wxl[ix] = lx * vx;
        wxh[ix] = (1.0f - lx) * vx;
        colx[ix] = xl;
    }

    __syncthreads();   // drains vmcnt; LDS plane ready

    // ---- gather + bilinear: pure ds_read2 + FMA ----
    float sum = 0.f;
    #pragma unroll
    for (int iy = 0; iy < 2; ++iy) {
        #pragma unroll
        for (int ix = 0; ix < 2; ++ix) {
            int a0 = rowa[iy] + colx[ix];
            int a1 = a0 + rstep[iy];
            float v11 = plane[a0];
            float v12 = plane[a0 + 1];
            float v21 = plane[a1];
            float v22 = plane[a1 + 1];
            float top = wxh[ix] * v11 + wxl[ix] * v12;
            float bot = wxh[ix] * v21 + wxl[ix] * v22;
            sum = fmaf(wyh[iy], top, sum);
            sum = fmaf(wyl[iy], bot, sum);
        }
    }
    ws[(size_t)p * NROI + n] = sum * 0.25f;   // coalesced
}

// Kernel 2: per-batch transpose ws[b][c][n] -> out[b][n][c].
#define TILE 32
__global__ __launch_bounds__(256) void transpose_kernel(
    const float* __restrict__ ws, float* __restrict__ out)
{
    __shared__ float tile[TILE][TILE + 1];
    int b  = blockIdx.z;
    int c0 = blockIdx.y * TILE;       // channel tile base (0..244)
    int n0 = blockIdx.x * TILE;       // roi tile base (0..511)
    const float* in = ws + (size_t)b * NCH * NROI;
    float* ob = out + (size_t)b * NROI * NCH;
    int tx = threadIdx.x;             // 0..31
    int ty = threadIdx.y;             // 0..7

    #pragma unroll
    for (int k = 0; k < 4; ++k) {
        int cc = c0 + ty + k * 8;
        if (cc < NCH) tile[ty + k * 8][tx] = in[(size_t)cc * NROI + n0 + tx];
    }
    __syncthreads();
    #pragma unroll
    for (int k = 0; k < 4; ++k) {
        int nn = n0 + ty + k * 8;
        int cc = c0 + tx;
        if (cc < NCH) ob[(size_t)nn * NCH + cc] = tile[tx][ty + k * 8];
    }
}

extern "C" void kernel_launch(void* const* d_in, const int* in_sizes, int n_in,
                              void* d_out, int out_size, void* d_ws, size_t ws_size,
                              hipStream_t stream) {
    const float* x     = (const float*)d_in[0];
    const float* boxes = (const float*)d_in[1];
    float* out = (float*)d_out;
    float* ws  = (float*)d_ws;       // 1960*512 f32 = 4 MB

    const int H = 100, W = 100;
    (void)in_sizes; (void)n_in; (void)out_size; (void)ws_size;

    hipLaunchKernelGGL(psroi_kernel, dim3(8 * NCH), dim3(512), 0, stream,
                       x, boxes, ws, H, W);
    hipLaunchKernelGGL(transpose_kernel, dim3(NROI / TILE, (NCH + TILE - 1) / TILE, 8),
                       dim3(TILE, 8), 0, stream, ws, out);
}

// Round 7
// 19.204 us; speedup vs baseline: 3.5997x; 1.1493x over previous
//
#include <hip/hip_runtime.h>

#define POOL 7
#define SCALE 0.0625f
#define HW 10000      // 100*100 plane elements
#define NROI 512
#define NCH 245

typedef const __attribute__((address_space(1))) void* gas_ptr;
typedef __attribute__((address_space(3))) void* las_ptr;

// One kernel. One block = one (b,c) plane, 512 threads = 512 rois.
// Block swizzle: bid = c*8 + b, so bid&7 = b -> all blocks of batch b land on
// XCD b (bid%8 round-robin heuristic). Every store to out[b] then merges in
// that XCD's private L2 (490 KB dirty working set << 4 MB), and each 64B
// output line is written back exactly once, fully populated -- this replaces
// the ws+transpose pair (12 MB extra traffic + one launch) with direct
// scattered stores that the L2 coalesces.
// Plane staged to LDS via global_load_lds (w=16, linear dest). Bilinear taps
// are paired reads (xl, xl+1): lx==0 exactly when xl==W-1, LDS pad zeroed.
__global__ __launch_bounds__(512) void psroi_kernel(
    const float* __restrict__ x, const float* __restrict__ boxes,
    float* __restrict__ out, int H, int W)
{
    __shared__ float plane[HW + 4];

    int bid = blockIdx.x;
    int b = bid & 7;             // batch == target XCD
    int c = bid >> 3;            // channel = d*49 + ph*7 + pw, 0..244
    int p = b * NCH + c;         // plane id in x
    int ph = (c / POOL) % POOL;
    int pw = c % POOL;

    int n = threadIdx.x;              // roi within batch [0,512)
    int r = b * NROI + n;             // global roi id

    // ---- boxes load first, then stage DMAs ----
    float4 bx = *(const float4*)(boxes + (size_t)r * 4);

    const float4* __restrict__ src4 = (const float4*)(x + (size_t)p * HW);
    int lane = threadIdx.x & 63;
    int wave = threadIdx.x >> 6;
    #pragma unroll
    for (int i = 0; i < 5; ++i) {
        int chunk_base = i * 512 + wave * 64;   // float4 units, wave-uniform
        int chunk = chunk_base + lane;
        if (chunk < HW / 4) {
            __builtin_amdgcn_global_load_lds(
                (gas_ptr)(src4 + chunk),
                (las_ptr)((char*)plane + (size_t)chunk_base * 16),
                16, 0, 0);
        }
    }
    if (threadIdx.x < 4) plane[HW + threadIdx.x] = 0.f;

    // ---- per-roi geometry (needs only boxes; runs under the DMA) ----
    float sw = bx.x * SCALE - 0.5f;
    float sh = bx.y * SCALE - 0.5f;
    float ew = bx.z * SCALE - 0.5f;
    float eh = bx.w * SCALE - 0.5f;
    float bin_h = (eh - sh) / (float)POOL;
    float bin_w = (ew - sw) / (float)POOL;
    float fy0 = sh + (float)ph * bin_h;
    float fx0 = sw + (float)pw * bin_w;

    int   rowa[2], rstep[2];
    float wyh[2], wyl[2];
    #pragma unroll
    for (int iy = 0; iy < 2; ++iy) {
        float y  = fy0 + ((float)iy + 0.5f) * bin_h * 0.5f;
        float vy = (y >= -1.0f && y <= (float)H) ? 1.0f : 0.0f;
        float yc = fminf(fmaxf(y, 0.0f), (float)(H - 1));
        int   yl = (int)floorf(yc);
        float ly = yc - (float)yl;
        wyl[iy] = ly * vy;
        wyh[iy] = (1.0f - ly) * vy;
        rowa[iy]  = yl * W;
        rstep[iy] = (yl < H - 1) ? W : 0;
    }
    int   colx[2];
    float wxh[2], wxl[2];
    #pragma unroll
    for (int ix = 0; ix < 2; ++ix) {
        float xf = fx0 + ((float)ix + 0.5f) * bin_w * 0.5f;
        float vx = (xf >= -1.0f && xf <= (float)W) ? 1.0f : 0.0f;
        float xc = fminf(fmaxf(xf, 0.0f), (float)(W - 1));
        int   xl = (int)floorf(xc);
        float lx = xc - (float)xl;      // == 0 exactly when xl == W-1
        wxl[ix] = lx * vx;
        wxh[ix] = (1.0f - lx) * vx;
        colx[ix] = xl;
    }

    __syncthreads();   // drains vmcnt; LDS plane ready

    // ---- gather + bilinear ----
    float sum = 0.f;
    #pragma unroll
    for (int iy = 0; iy < 2; ++iy) {
        #pragma unroll
        for (int ix = 0; ix < 2; ++ix) {
            int a0 = rowa[iy] + colx[ix];
            int a1 = a0 + rstep[iy];
            float v11 = plane[a0];
            float v12 = plane[a0 + 1];
            float v21 = plane[a1];
            float v22 = plane[a1 + 1];
            float top = wxh[ix] * v11 + wxl[ix] * v12;
            float bot = wxh[ix] * v21 + wxl[ix] * v22;
            sum = fmaf(wyh[iy], top, sum);
            sum = fmaf(wyl[iy], bot, sum);
        }
    }
    // direct scattered store; merges in XCD-local L2 (see header comment)
    out[(size_t)r * NCH + c] = sum * 0.25f;
}

extern "C" void kernel_launch(void* const* d_in, const int* in_sizes, int n_in,
                              void* d_out, int out_size, void* d_ws, size_t ws_size,
                              hipStream_t stream) {
    const float* x     = (const float*)d_in[0];
    const float* boxes = (const float*)d_in[1];
    float* out = (float*)d_out;

    const int H = 100, W = 100;
    (void)in_sizes; (void)n_in; (void)out_size; (void)d_ws; (void)ws_size;

    hipLaunchKernelGGL(psroi_kernel, dim3(NCH * 8), dim3(512), 0, stream,
                       x, boxes, out, H, W);
}